// Round 1
// 426.024 us; speedup vs baseline: 1.0499x; 1.0499x over previous
//
#include <hip/hip_runtime.h>

// Problem constants
#define B_   1024
#define E_   200
#define NE_  50000
#define OC_  32
#define FW_  9
#define WP_  192
#define FCIN 6144   // OC*WP
#define CATK 400    // E+R
#define KDIM 288    // OC*FW

typedef __attribute__((ext_vector_type(8))) short short8;
typedef __attribute__((ext_vector_type(4))) float floatx4;
typedef __attribute__((ext_vector_type(4))) unsigned short ushort4v;

static __device__ __forceinline__ float bf2f(unsigned short u) {
  return __uint_as_float(((unsigned)u) << 16);
}
static __device__ __forceinline__ unsigned short f2bf(float f) {
  unsigned u = __float_as_uint(f);
  u += 0x7FFFu + ((u >> 16) & 1u);   // RNE
  return (unsigned short)(u >> 16);
}

// ---------------- fp32 -> bf16 bulk convert (float4 in, ushort4 out) ----------------
__global__ __launch_bounds__(256) void k_cvt(
    const float* __restrict__ in, unsigned short* __restrict__ out, int n4) {
  int i = blockIdx.x * 256 + threadIdx.x;
  if (i >= n4) return;
  float4 v = ((const float4*)in)[i];
  ushort4v o = {f2bf(v.x), f2bf(v.y), f2bf(v.z), f2bf(v.w)};
  ((ushort4v*)out)[i] = o;
}

// ---------------- gather+convert: cat[1024][400] (es|ec), rbuf[1024][200] ----------------
__global__ __launch_bounds__(256) void k_gather(
    const int* __restrict__ e_s, const int* __restrict__ q_s, const int* __restrict__ e_c,
    const float* __restrict__ ent, const float* __restrict__ rel,
    unsigned short* __restrict__ cat, unsigned short* __restrict__ rbuf) {
  int idx = blockIdx.x * 256 + threadIdx.x;
  if (idx < B_ * CATK) {
    int s = idx / CATK, i = idx - s * CATK;
    int row = (i < E_) ? e_s[s] : e_c[s];
    int col = (i < E_) ? i : i - E_;
    cat[idx] = f2bf(ent[row * E_ + col]);
  } else {
    int j = idx - B_ * CATK;
    if (j < B_ * E_) {
      int s = j / E_, i = j - s * E_;
      rbuf[j] = f2bf(rel[q_s[s] * E_ + i]);
    }
  }
}

// ------- LDS tile transpose+pad+convert: in[k*N+n] fp32 -> out[n*K+k] bf16 (n<Npad) -------
// Coalesced on both sides. Grid: (ceil(Npad/64), ceil(K/64)).
__global__ __launch_bounds__(256) void k_transpose_lds(
    const float* __restrict__ in, unsigned short* __restrict__ out,
    int N, int Npad, int K) {
  __shared__ unsigned short lds[64][65];
  int n0 = blockIdx.x * 64, k0 = blockIdx.y * 64;
  int tx = threadIdx.x & 63, ty = threadIdx.x >> 6;   // ty in 0..3
#pragma unroll
  for (int kk = 0; kk < 16; kk++) {
    int k = k0 + ty + 4 * kk;
    int n = n0 + tx;
    unsigned short v = 0;
    if (k < K && n < N) v = f2bf(in[(long)k * N + n]);
    lds[ty + 4 * kk][tx] = v;
  }
  __syncthreads();
#pragma unroll
  for (int kk = 0; kk < 16; kk++) {
    int k = k0 + tx;
    int n = n0 + ty + 4 * kk;
    if (n < Npad && k < K) out[(long)n * K + k] = lds[tx][ty + 4 * kk];
  }
}

// ---------------- shared 64x16 GEMM tile (4 waves; wave w = rows m0+16w..+15) ----------------
// A: [M][lda] bf16 row-major. Bt: [n][ldb] bf16 (row n = col n of B). K = NK*32 + RQ*8.
template<int NK, int RQ>
static __device__ __forceinline__ floatx4 gemm_64x16(
    const unsigned short* __restrict__ A, int lda,
    const unsigned short* __restrict__ Bt, int ldb, int m0, int n0) {
  int lane = threadIdx.x & 63;
  int wv   = threadIdx.x >> 6;
  int l16  = lane & 15, quad = lane >> 4;
  const unsigned short* ap = A  + (long)(m0 + 16 * wv + l16) * lda + quad * 8;
  const unsigned short* bp = Bt + (long)(n0 + l16) * ldb + quad * 8;
  floatx4 acc = {0.f, 0.f, 0.f, 0.f};
#pragma unroll 4
  for (int ks = 0; ks < NK; ks++) {
    short8 a = *(const short8*)(ap + ks * 32);
    short8 b = *(const short8*)(bp + ks * 32);
    acc = __builtin_amdgcn_mfma_f32_16x16x32_bf16(a, b, acc, 0, 0, 0);
  }
  if (RQ > 0) {  // K remainder: quads < RQ hold real data, rest contribute zeros
    short8 z = {0,0,0,0,0,0,0,0};
    short8 a = (quad < RQ) ? *(const short8*)(ap + NK * 32) : z;
    short8 b = (quad < RQ) ? *(const short8*)(bp + NK * 32) : z;
    acc = __builtin_amdgcn_mfma_f32_16x16x32_bf16(a, b, acc, 0, 0, 0);
  }
  return acc;
}

// ---------------- e1 = cat @ W1 + W1_b ; bn0 -> xbuf[1024][200] bf16 ----------------
// K=400 = 12*32 + 2*8
__global__ __launch_bounds__(256) void k_gemm_e1(
    const unsigned short* __restrict__ cat, const unsigned short* __restrict__ W1T,
    const float* __restrict__ W1b,
    const float* __restrict__ g0, const float* __restrict__ b0,
    const float* __restrict__ m0p, const float* __restrict__ v0,
    unsigned short* __restrict__ xbuf) {
  int m0 = blockIdx.x * 64, n0 = blockIdx.y * 16;
  floatx4 acc = gemm_64x16<12, 2>(cat, CATK, W1T, CATK, m0, n0);
  int lane = threadIdx.x & 63, wv = threadIdx.x >> 6;
  int l16 = lane & 15, quad = lane >> 4;
  int j = n0 + l16;
  if (j < E_) {
    float s0  = g0[0] * rsqrtf(v0[0] + 1e-5f);
    float off = (W1b[j] - m0p[0]) * s0 + b0[0];
    int rbase = m0 + 16 * wv + quad * 4;
#pragma unroll
    for (int i = 0; i < 4; i++)
      xbuf[(rbase + i) * E_ + j] = f2bf(acc[i] * s0 + off);
  }
}

// ------- ktil = (r @ fc1_w + fc1_b) * s1[o] -> kbuf[1024][288] bf16 (bn1 scale folded) -------
// K=200 = 6*32 + 1*8
__global__ __launch_bounds__(256) void k_gemm_k(
    const unsigned short* __restrict__ rbuf, const unsigned short* __restrict__ fc1T,
    const float* __restrict__ fc1b,
    const float* __restrict__ g1, const float* __restrict__ v1,
    unsigned short* __restrict__ kbuf) {
  int m0 = blockIdx.x * 64, n0 = blockIdx.y * 16;
  floatx4 acc = gemm_64x16<6, 1>(rbuf, E_, fc1T, E_, m0, n0);
  int lane = threadIdx.x & 63, wv = threadIdx.x >> 6;
  int l16 = lane & 15, quad = lane >> 4;
  int c = n0 + l16;              // < 288 always (288 = 18*16)
  int o = c / FW_;
  float s1 = g1[o] * rsqrtf(v1[o] + 1e-5f);
  float fb = fc1b[c];
  int rbase = m0 + 16 * wv + quad * 4;
#pragma unroll
  for (int i = 0; i < 4; i++)
    kbuf[(rbase + i) * KDIM + c] = f2bf((acc[i] + fb) * s1);
}

// ---------------- per-sample conv + bn1 bias -> flat[1024][6144] bf16 ----------------
__global__ __launch_bounds__(256) void k_conv(
    const unsigned short* __restrict__ xbuf, const unsigned short* __restrict__ kbuf,
    const float* __restrict__ g1, const float* __restrict__ b1,
    const float* __restrict__ m1, const float* __restrict__ v1,
    unsigned short* __restrict__ flat) {
  __shared__ float xs[E_];
  __shared__ float ks[KDIM];
  __shared__ float beta[OC_];
  int b = blockIdx.x, tid = threadIdx.x;
  if (tid < E_)  xs[tid] = bf2f(xbuf[b * E_ + tid]);
  for (int i = tid; i < KDIM; i += 256) ks[i] = bf2f(kbuf[b * KDIM + i]);
  if (tid < OC_) {
    float s = g1[tid] * rsqrtf(v1[tid] + 1e-5f);
    beta[tid] = b1[tid] - m1[tid] * s;
  }
  __syncthreads();
#pragma unroll
  for (int u = 0; u < FCIN / 256; u++) {
    int t = u * 256 + tid;
    int o = t / WP_, p = t - o * WP_;
    float acc = beta[o];
#pragma unroll
    for (int w = 0; w < FW_; w++) acc += xs[p + w] * ks[o * FW_ + w];
    flat[b * FCIN + t] = f2bf(acc);
  }
}

// ------------- flat @ fc_w, split-K x8 -> partial[8][1024][208] fp32 -------------
// K-chunk = 768 = 24*32. Grid (16, 13, 8).
__global__ __launch_bounds__(256) void k_gemm_fc(
    const unsigned short* __restrict__ flat, const unsigned short* __restrict__ fcwT,
    float* __restrict__ partial) {
  int m0 = blockIdx.x * 64, n0 = blockIdx.y * 16, kc = blockIdx.z;
  int lane = threadIdx.x & 63, wv = threadIdx.x >> 6;
  int l16 = lane & 15, quad = lane >> 4;
  const unsigned short* ap = flat + (long)(m0 + 16 * wv + l16) * FCIN + kc * 768 + quad * 8;
  const unsigned short* bp = fcwT + (long)(n0 + l16) * FCIN + kc * 768 + quad * 8;
  floatx4 acc = {0.f, 0.f, 0.f, 0.f};
#pragma unroll 4
  for (int ks = 0; ks < 24; ks++) {
    short8 a = *(const short8*)(ap + ks * 32);
    short8 b = *(const short8*)(bp + ks * 32);
    acc = __builtin_amdgcn_mfma_f32_16x16x32_bf16(a, b, acc, 0, 0, 0);
  }
  int j = n0 + l16;   // < 208 always
  int rbase = m0 + 16 * wv + quad * 4;
#pragma unroll
  for (int i = 0; i < 4; i++)
    partial[((long)kc * B_ + rbase + i) * 208 + j] = acc[i];
}

// ------------- reduce partials + bias + bn2 + relu -> hbuf[1024][200] bf16 -------------
__global__ __launch_bounds__(256) void k_fc_epi(
    const float* __restrict__ partial, const float* __restrict__ fcb,
    const float* __restrict__ g2, const float* __restrict__ b2,
    const float* __restrict__ m2, const float* __restrict__ v2,
    unsigned short* __restrict__ hbuf) {
  int idx = blockIdx.x * 256 + threadIdx.x;
  if (idx >= B_ * E_) return;
  int m = idx / E_, j = idx - m * E_;
  float s = 0.f;
#pragma unroll
  for (int kc = 0; kc < 8; kc++) s += partial[((long)kc * B_ + m) * 208 + j];
  float s2 = g2[j] * rsqrtf(v2[j] + 1e-5f);
  float h = (s + fcb[j] - m2[j]) * s2 + b2[j];
  hbuf[idx] = f2bf(fmaxf(h, 0.f));
}

// ---------------- out = sigmoid(h @ entity^T + bias) -> d_out[1024][50000] fp32 ----------------
// 256m x 128n tile, 512 threads (8 waves, each owns 32 rows x 128 cols).
// B (entity tile, 128 cols x K=200) is staged ONCE per block into LDS in
// fragment-major layout Blds[ks(7)][quad(4)][np(128)][8 bf16] (57,344 B), with
// np = nf*16 + l16 <-> entity col 8*l16 + nf (column-interleaved so each lane
// owns 8 consecutive output floats -> 2x dwordx4 stores). The ds_read_b128
// address set is exactly 8 dwords per bank (balanced -> no conflict penalty).
// K zero-padded to 224 (ks=6, quad>0 chunks are zeros) so the B side of the
// k-loop is uniform; the A remainder masks quads 1..3 to zero as before.
// vs. previous 128x64/no-LDS version: B L2 traffic 640->160 MB, A 320->160 MB.
// Grid: 1564 = 4 m-tiles x 391 n-tiles. Bijective XCD swizzle (8 XCDs,
// q=195, r=4): each XCD owns ~49 contiguous n-tiles (entb slice ~2.5 MB fits
// 4 MB XCD L2); consecutive local blocks reuse one n-tile across 4 m-tiles.
// launch_bounds(512,4): cap 128 VGPR (est ~105 live) -> 2 blocks/CU so one
// block's LDS staging hides under the other's MFMA phase.
__global__ __launch_bounds__(512, 4) void k_gemm_out(
    const unsigned short* __restrict__ hbuf, const unsigned short* __restrict__ entb,
    const float* __restrict__ bias, float* __restrict__ out) {
  __shared__ __align__(16) unsigned short Blds[7 * 4 * 128 * 8];  // 57,344 B
  int g = blockIdx.x;                       // 0..1563
  int xcd = g & 7, local_ = g >> 3;         // dispatch round-robins XCDs
  int T = (xcd < 4 ? xcd * 196 : 784 + (xcd - 4) * 195) + local_;
  int mt = T & 3, nt = T >> 2;
  int m0 = mt * 256, n0 = nt * 128;
  int tid = threadIdx.x;

  // ---- stage B tile: 3584 chunks of 16 B, fragment-major, zero-padded ----
#pragma unroll
  for (int it = 0; it < 7; ++it) {
    int idx = it * 512 + tid;               // [ks][quad][np]
    int ks = idx >> 9, qd = (idx >> 7) & 3, np = idx & 127;
    int col = 8 * (np & 15) + (np >> 4);    // interleaved col within n-tile
    int n = n0 + col;
    int kb = ks * 32 + qd * 8;
    short8 v = {0, 0, 0, 0, 0, 0, 0, 0};
    if (kb < 200 && n < NE_) v = *(const short8*)(entb + (long)n * E_ + kb);
    *(short8*)(Blds + idx * 8) = v;
  }
  __syncthreads();

  int lane = tid & 63, wv = tid >> 6;       // wv 0..7
  int l16 = lane & 15, quad = lane >> 4;
  const unsigned short* ap0 = hbuf + (long)(m0 + wv * 32 + l16) * E_ + quad * 8;
  const unsigned short* ap1 = ap0 + 16 * E_;

  floatx4 acc[16];
#pragma unroll
  for (int i = 0; i < 16; ++i) acc[i] = (floatx4){0.f, 0.f, 0.f, 0.f};

#pragma unroll
  for (int ks = 0; ks < 6; ++ks) {
    short8 a0 = *(const short8*)(ap0 + ks * 32);
    short8 a1 = *(const short8*)(ap1 + ks * 32);
    const unsigned short* bb = Blds + (ks * 4 + quad) * 1024 + l16 * 8;
#pragma unroll
    for (int nf = 0; nf < 8; ++nf) {
      short8 b = *(const short8*)(bb + nf * 128);
      acc[nf]     = __builtin_amdgcn_mfma_f32_16x16x32_bf16(a0, b, acc[nf], 0, 0, 0);
      acc[8 + nf] = __builtin_amdgcn_mfma_f32_16x16x32_bf16(a1, b, acc[8 + nf], 0, 0, 0);
    }
  }
  { // k remainder 192..199: A real on quad 0 only; B pad chunks are zeros
    short8 z = {0, 0, 0, 0, 0, 0, 0, 0};
    short8 a0 = (quad == 0) ? *(const short8*)(ap0 + 192) : z;
    short8 a1 = (quad == 0) ? *(const short8*)(ap1 + 192) : z;
    const unsigned short* bb = Blds + (24 + quad) * 1024 + l16 * 8;
#pragma unroll
    for (int nf = 0; nf < 8; ++nf) {
      short8 b = *(const short8*)(bb + nf * 128);
      acc[nf]     = __builtin_amdgcn_mfma_f32_16x16x32_bf16(a0, b, acc[nf], 0, 0, 0);
      acc[8 + nf] = __builtin_amdgcn_mfma_f32_16x16x32_bf16(a1, b, acc[8 + nf], 0, 0, 0);
    }
  }

  int nb = n0 + 8 * l16;                    // lane's base output col (8-aligned)
  if (nb >= NE_) return;                    // NE%8==0 -> whole 8-col group valid or not
  float4 bi0 = *(const float4*)(bias + nb);
  float4 bi1 = *(const float4*)(bias + nb + 4);
#pragma unroll
  for (int mf = 0; mf < 2; ++mf) {
#pragma unroll
    for (int i = 0; i < 4; ++i) {
      int row = m0 + wv * 32 + mf * 16 + quad * 4 + i;
      float4 v0, v1;
      v0.x = 1.f / (1.f + __expf(-(acc[mf * 8 + 0][i] + bi0.x)));
      v0.y = 1.f / (1.f + __expf(-(acc[mf * 8 + 1][i] + bi0.y)));
      v0.z = 1.f / (1.f + __expf(-(acc[mf * 8 + 2][i] + bi0.z)));
      v0.w = 1.f / (1.f + __expf(-(acc[mf * 8 + 3][i] + bi0.w)));
      v1.x = 1.f / (1.f + __expf(-(acc[mf * 8 + 4][i] + bi1.x)));
      v1.y = 1.f / (1.f + __expf(-(acc[mf * 8 + 5][i] + bi1.y)));
      v1.z = 1.f / (1.f + __expf(-(acc[mf * 8 + 6][i] + bi1.z)));
      v1.w = 1.f / (1.f + __expf(-(acc[mf * 8 + 7][i] + bi1.w)));
      float* op = out + (long)row * NE_ + nb;
      *(float4*)op = v0;
      *(float4*)(op + 4) = v1;
    }
  }
}

extern "C" void kernel_launch(void* const* d_in, const int* in_sizes, int n_in,
                              void* d_out, int out_size, void* d_ws, size_t ws_size,
                              hipStream_t stream) {
  const int* e_s = (const int*)d_in[0];
  const int* q_s = (const int*)d_in[1];
  const int* e_c = (const int*)d_in[2];
  const float* ent  = (const float*)d_in[3];
  const float* rel  = (const float*)d_in[4];
  const float* W1w  = (const float*)d_in[5];
  const float* W1b  = (const float*)d_in[6];
  const float* fc1w = (const float*)d_in[7];
  const float* fc1b = (const float*)d_in[8];
  const float* fcw  = (const float*)d_in[9];
  const float* fcb  = (const float*)d_in[10];
  const float* g0 = (const float*)d_in[11];
  const float* b0 = (const float*)d_in[12];
  const float* m0 = (const float*)d_in[13];
  const float* v0 = (const float*)d_in[14];
  const float* g1 = (const float*)d_in[15];
  const float* b1 = (const float*)d_in[16];
  const float* m1 = (const float*)d_in[17];
  const float* v1 = (const float*)d_in[18];
  const float* g2 = (const float*)d_in[19];
  const float* b2 = (const float*)d_in[20];
  const float* m2 = (const float*)d_in[21];
  const float* v2 = (const float*)d_in[22];
  const float* bias = (const float*)d_in[23];
  float* out = (float*)d_out;

  // Workspace layout (256 B padded regions; total ~44.9 MB)
  char* w = (char*)d_ws;
  unsigned short* entb = (unsigned short*)(w + 0);          // 20,000,000 B [50000][200]
  unsigned short* cat  = (unsigned short*)(w + 20000256);   //    819,200 B [1024][400]
  unsigned short* rbuf = (unsigned short*)(w + 20819712);   //    409,600 B [1024][200]
  unsigned short* W1T  = (unsigned short*)(w + 21229568);   //    166,400 B [208][400]
  unsigned short* fc1T = (unsigned short*)(w + 21396224);   //    115,200 B [288][200]
  unsigned short* fcwT = (unsigned short*)(w + 21511680);   //  2,555,904 B [208][6144]
  unsigned short* xbuf = (unsigned short*)(w + 24067840);   //    409,600 B [1024][200]
  unsigned short* kbuf = (unsigned short*)(w + 24477696);   //    589,824 B [1024][288]
  unsigned short* flat = (unsigned short*)(w + 25067776);   // 12,582,912 B [1024][6144]
  unsigned short* hbuf = (unsigned short*)(w + 37650944);   //    409,600 B [1024][200]
  float* partial       = (float*)(w + 38060800);            //  6,815,744 B [8][1024][208]
  // end = 44,876,544

  k_cvt<<<dim3((NE_ * E_ / 4 + 255) / 256), dim3(256), 0, stream>>>(ent, entb, NE_ * E_ / 4);
  k_gather<<<dim3((B_ * CATK + B_ * E_) / 256), dim3(256), 0, stream>>>(
      e_s, q_s, e_c, ent, rel, cat, rbuf);
  k_transpose_lds<<<dim3(4, 7),  dim3(256), 0, stream>>>(W1w,  W1T,  200, 208, CATK);
  k_transpose_lds<<<dim3(5, 4),  dim3(256), 0, stream>>>(fc1w, fc1T, 288, 288, E_);
  k_transpose_lds<<<dim3(4, 96), dim3(256), 0, stream>>>(fcw,  fcwT, 200, 208, FCIN);

  k_gemm_e1<<<dim3(16, 13), dim3(256), 0, stream>>>(cat, W1T, W1b, g0, b0, m0, v0, xbuf);
  k_gemm_k<<<dim3(16, 18), dim3(256), 0, stream>>>(rbuf, fc1T, fc1b, g1, v1, kbuf);
  k_conv<<<dim3(B_), dim3(256), 0, stream>>>(xbuf, kbuf, g1, b1, m1, v1, flat);
  k_gemm_fc<<<dim3(16, 13, 8), dim3(256), 0, stream>>>(flat, fcwT, partial);
  k_fc_epi<<<dim3((B_ * E_ + 255) / 256), dim3(256), 0, stream>>>(
      partial, fcb, g2, b2, m2, v2, hbuf);
  k_gemm_out<<<dim3(1564), dim3(512), 0, stream>>>(hbuf, entb, bias, out);
}

// Round 2
// 392.327 us; speedup vs baseline: 1.1401x; 1.0859x over previous
//
#include <hip/hip_runtime.h>

// Problem constants
#define B_   1024
#define E_   200
#define NE_  50000
#define OC_  32
#define FW_  9
#define WP_  192
#define FCIN 6144   // OC*WP
#define CATK 400    // E+R
#define KDIM 288    // OC*FW

typedef __attribute__((ext_vector_type(8))) short short8;
typedef __attribute__((ext_vector_type(4))) float floatx4;
typedef __attribute__((ext_vector_type(4))) unsigned short ushort4v;

static __device__ __forceinline__ float bf2f(unsigned short u) {
  return __uint_as_float(((unsigned)u) << 16);
}
static __device__ __forceinline__ unsigned short f2bf(float f) {
  unsigned u = __float_as_uint(f);
  u += 0x7FFFu + ((u >> 16) & 1u);   // RNE
  return (unsigned short)(u >> 16);
}

// ---------------- fused prep: cvt + gather + 3 transposes in ONE launch ----------------
// All five regions are mutually independent; region picked by blockIdx.x range.
// Saves 4 kernel-launch gaps vs the previous 5 separate dispatches.
#define PREP_CVT_BLKS   9766   // ceil(2,500,000/256)
#define PREP_GATH_BLKS  2400   // (B*CATK + B*E)/256 exactly
#define PREP_W1_BLKS    28     // (4 x 7)
#define PREP_FC1_BLKS   20     // (5 x 4)
#define PREP_FCW_BLKS   384    // (4 x 96)
#define PREP_R1 (PREP_CVT_BLKS)
#define PREP_R2 (PREP_R1 + PREP_GATH_BLKS)
#define PREP_R3 (PREP_R2 + PREP_W1_BLKS)
#define PREP_R4 (PREP_R3 + PREP_FC1_BLKS)
#define PREP_TOTAL (PREP_R4 + PREP_FCW_BLKS)   // 12598

// LDS tile transpose+pad+convert: in[k*N+n] fp32 -> out[n*K+k] bf16 (n<Npad).
// Coalesced on both sides; whole block takes this branch so __syncthreads is safe.
static __device__ __forceinline__ void transpose_region(
    const float* __restrict__ in, unsigned short* __restrict__ out,
    int N, int Npad, int K, int bx, int by,
    unsigned short (*lds)[65]) {
  int n0 = bx * 64, k0 = by * 64;
  int tx = threadIdx.x & 63, ty = threadIdx.x >> 6;   // ty in 0..3
#pragma unroll
  for (int kk = 0; kk < 16; kk++) {
    int k = k0 + ty + 4 * kk;
    int n = n0 + tx;
    unsigned short v = 0;
    if (k < K && n < N) v = f2bf(in[(long)k * N + n]);
    lds[ty + 4 * kk][tx] = v;
  }
  __syncthreads();
#pragma unroll
  for (int kk = 0; kk < 16; kk++) {
    int k = k0 + tx;
    int n = n0 + ty + 4 * kk;
    if (n < Npad && k < K) out[(long)n * K + k] = lds[tx][ty + 4 * kk];
  }
}

__global__ __launch_bounds__(256) void k_prep(
    const float* __restrict__ ent, const float* __restrict__ rel,
    const int* __restrict__ e_s, const int* __restrict__ q_s, const int* __restrict__ e_c,
    const float* __restrict__ W1w, const float* __restrict__ fc1w, const float* __restrict__ fcw,
    unsigned short* __restrict__ entb, unsigned short* __restrict__ cat,
    unsigned short* __restrict__ rbuf, unsigned short* __restrict__ W1T,
    unsigned short* __restrict__ fc1T, unsigned short* __restrict__ fcwT) {
  __shared__ unsigned short lds[64][65];
  int blk = blockIdx.x, tid = threadIdx.x;
  if (blk < PREP_R1) {
    // fp32 -> bf16 bulk convert of entity_emb (float4 in, ushort4 out)
    int i = blk * 256 + tid;
    if (i < NE_ * E_ / 4) {
      float4 v = ((const float4*)ent)[i];
      ushort4v o = {f2bf(v.x), f2bf(v.y), f2bf(v.z), f2bf(v.w)};
      ((ushort4v*)entb)[i] = o;
    }
  } else if (blk < PREP_R2) {
    // gather+convert: cat[1024][400] (es|ec), rbuf[1024][200]
    int idx = (blk - PREP_R1) * 256 + tid;
    if (idx < B_ * CATK) {
      int s = idx / CATK, i = idx - s * CATK;
      int row = (i < E_) ? e_s[s] : e_c[s];
      int col = (i < E_) ? i : i - E_;
      cat[idx] = f2bf(ent[row * E_ + col]);
    } else {
      int j = idx - B_ * CATK;   // < B_*E_ by region sizing
      int s = j / E_, i = j - s * E_;
      rbuf[j] = f2bf(rel[q_s[s] * E_ + i]);
    }
  } else if (blk < PREP_R3) {
    int l = blk - PREP_R2;
    transpose_region(W1w, W1T, 200, 208, CATK, l % 4, l / 4, lds);
  } else if (blk < PREP_R4) {
    int l = blk - PREP_R3;
    transpose_region(fc1w, fc1T, 288, 288, E_, l % 5, l / 5, lds);
  } else {
    int l = blk - PREP_R4;
    transpose_region(fcw, fcwT, 200, 208, FCIN, l % 4, l / 4, lds);
  }
}

// ---------------- shared 64x16 GEMM tile (4 waves; wave w = rows m0+16w..+15) ----------------
// A: [M][lda] bf16 row-major. Bt: [n][ldb] bf16 (row n = col n of B). K = NK*32 + RQ*8.
template<int NK, int RQ>
static __device__ __forceinline__ floatx4 gemm_64x16(
    const unsigned short* __restrict__ A, int lda,
    const unsigned short* __restrict__ Bt, int ldb, int m0, int n0) {
  int lane = threadIdx.x & 63;
  int wv   = threadIdx.x >> 6;
  int l16  = lane & 15, quad = lane >> 4;
  const unsigned short* ap = A  + (long)(m0 + 16 * wv + l16) * lda + quad * 8;
  const unsigned short* bp = Bt + (long)(n0 + l16) * ldb + quad * 8;
  floatx4 acc = {0.f, 0.f, 0.f, 0.f};
#pragma unroll 4
  for (int ks = 0; ks < NK; ks++) {
    short8 a = *(const short8*)(ap + ks * 32);
    short8 b = *(const short8*)(bp + ks * 32);
    acc = __builtin_amdgcn_mfma_f32_16x16x32_bf16(a, b, acc, 0, 0, 0);
  }
  if (RQ > 0) {  // K remainder: quads < RQ hold real data, rest contribute zeros
    short8 z = {0,0,0,0,0,0,0,0};
    short8 a = (quad < RQ) ? *(const short8*)(ap + NK * 32) : z;
    short8 b = (quad < RQ) ? *(const short8*)(bp + NK * 32) : z;
    acc = __builtin_amdgcn_mfma_f32_16x16x32_bf16(a, b, acc, 0, 0, 0);
  }
  return acc;
}

// ------- fused e1-GEMM + k-GEMM (independent; region by blockIdx) -------
// Region A (208 blocks): e1 = cat @ W1 + W1_b ; bn0 -> xbuf[1024][200] bf16. K=400=12*32+2*8
// Region B (288 blocks): ktil = (r @ fc1_w + fc1_b)*s1[o] -> kbuf[1024][288] bf16. K=200=6*32+1*8
__global__ __launch_bounds__(256) void k_gemm_ek(
    const unsigned short* __restrict__ cat, const unsigned short* __restrict__ W1T,
    const float* __restrict__ W1b,
    const float* __restrict__ g0, const float* __restrict__ b0,
    const float* __restrict__ m0p, const float* __restrict__ v0,
    unsigned short* __restrict__ xbuf,
    const unsigned short* __restrict__ rbuf, const unsigned short* __restrict__ fc1T,
    const float* __restrict__ fc1b,
    const float* __restrict__ g1, const float* __restrict__ v1,
    unsigned short* __restrict__ kbuf) {
  int blk = blockIdx.x;
  int lane = threadIdx.x & 63, wv = threadIdx.x >> 6;
  int l16 = lane & 15, quad = lane >> 4;
  if (blk < 208) {
    int m0 = (blk & 15) * 64, n0 = (blk >> 4) * 16;
    floatx4 acc = gemm_64x16<12, 2>(cat, CATK, W1T, CATK, m0, n0);
    int j = n0 + l16;
    if (j < E_) {
      float s0  = g0[0] * rsqrtf(v0[0] + 1e-5f);
      float off = (W1b[j] - m0p[0]) * s0 + b0[0];
      int rbase = m0 + 16 * wv + quad * 4;
#pragma unroll
      for (int i = 0; i < 4; i++)
        xbuf[(rbase + i) * E_ + j] = f2bf(acc[i] * s0 + off);
    }
  } else {
    int l = blk - 208;
    int m0 = (l & 15) * 64, n0 = (l >> 4) * 16;
    floatx4 acc = gemm_64x16<6, 1>(rbuf, E_, fc1T, E_, m0, n0);
    int c = n0 + l16;              // < 288 always (288 = 18*16)
    int o = c / FW_;
    float s1 = g1[o] * rsqrtf(v1[o] + 1e-5f);
    float fb = fc1b[c];
    int rbase = m0 + 16 * wv + quad * 4;
#pragma unroll
    for (int i = 0; i < 4; i++)
      kbuf[(rbase + i) * KDIM + c] = f2bf((acc[i] + fb) * s1);
  }
}

// ---------------- per-sample conv + bn1 bias -> flat[1024][6144] bf16 ----------------
// Thread owns (o, p-chunk): o = tid>>3, p-chunk pc = tid&7 covers p in [24*pc, 24*pc+24).
// x-window (32 floats) loaded ONCE via 8x ds_read_b128; 9 filter taps loaded once.
// All 216 FMAs are register-resident: ~20 LDS instructions/thread vs 432 before.
// FMA order per output identical to previous version -> bitwise-identical results.
__global__ __launch_bounds__(256) void k_conv(
    const unsigned short* __restrict__ xbuf, const unsigned short* __restrict__ kbuf,
    const float* __restrict__ g1, const float* __restrict__ b1,
    const float* __restrict__ m1, const float* __restrict__ v1,
    unsigned short* __restrict__ flat) {
  __shared__ float xs[E_];
  __shared__ float ks[KDIM];
  __shared__ float beta[OC_];
  int b = blockIdx.x, tid = threadIdx.x;
  if (tid < E_)  xs[tid] = bf2f(xbuf[b * E_ + tid]);
  for (int i = tid; i < KDIM; i += 256) ks[i] = bf2f(kbuf[b * KDIM + i]);
  if (tid < OC_) {
    float s = g1[tid] * rsqrtf(v1[tid] + 1e-5f);
    beta[tid] = b1[tid] - m1[tid] * s;
  }
  __syncthreads();
  int o = tid >> 3, pc = tid & 7;
  int p0 = pc * 24;                         // 24*4 B = 96 B: 16B-aligned -> float4 LDS reads
  float kw[FW_];
#pragma unroll
  for (int w = 0; w < FW_; w++) kw[w] = ks[o * FW_ + w];
  float xw[32];                             // xs[p0 .. p0+31] (p0 max 168 -> 199 in range)
#pragma unroll
  for (int q = 0; q < 8; q++) {
    float4 v = *(const float4*)&xs[p0 + 4 * q];
    xw[4 * q + 0] = v.x; xw[4 * q + 1] = v.y; xw[4 * q + 2] = v.z; xw[4 * q + 3] = v.w;
  }
  float bo = beta[o];
  unsigned short* fp = flat + b * FCIN + o * WP_ + p0;
#pragma unroll
  for (int j = 0; j < 24; j += 2) {
    float a0 = bo, a1 = bo;
#pragma unroll
    for (int w = 0; w < FW_; w++) {
      a0 += xw[j + w] * kw[w];
      a1 += xw[j + 1 + w] * kw[w];
    }
    unsigned pack = (unsigned)f2bf(a0) | ((unsigned)f2bf(a1) << 16);
    *(unsigned*)(fp + j) = pack;            // offset even -> 4B aligned
  }
}

// ------------- flat @ fc_w, split-K x8 -> partial[8][1024][208] fp32 -------------
// K-chunk = 768 = 24*32. Grid (16, 13, 8).
__global__ __launch_bounds__(256) void k_gemm_fc(
    const unsigned short* __restrict__ flat, const unsigned short* __restrict__ fcwT,
    float* __restrict__ partial) {
  int m0 = blockIdx.x * 64, n0 = blockIdx.y * 16, kc = blockIdx.z;
  int lane = threadIdx.x & 63, wv = threadIdx.x >> 6;
  int l16 = lane & 15, quad = lane >> 4;
  const unsigned short* ap = flat + (long)(m0 + 16 * wv + l16) * FCIN + kc * 768 + quad * 8;
  const unsigned short* bp = fcwT + (long)(n0 + l16) * FCIN + kc * 768 + quad * 8;
  floatx4 acc = {0.f, 0.f, 0.f, 0.f};
#pragma unroll 4
  for (int ks = 0; ks < 24; ks++) {
    short8 a = *(const short8*)(ap + ks * 32);
    short8 b = *(const short8*)(bp + ks * 32);
    acc = __builtin_amdgcn_mfma_f32_16x16x32_bf16(a, b, acc, 0, 0, 0);
  }
  int j = n0 + l16;   // < 208 always
  int rbase = m0 + 16 * wv + quad * 4;
#pragma unroll
  for (int i = 0; i < 4; i++)
    partial[((long)kc * B_ + rbase + i) * 208 + j] = acc[i];
}

// ------------- reduce partials + bias + bn2 + relu -> hbuf[1024][200] bf16 -------------
__global__ __launch_bounds__(256) void k_fc_epi(
    const float* __restrict__ partial, const float* __restrict__ fcb,
    const float* __restrict__ g2, const float* __restrict__ b2,
    const float* __restrict__ m2, const float* __restrict__ v2,
    unsigned short* __restrict__ hbuf) {
  int idx = blockIdx.x * 256 + threadIdx.x;
  if (idx >= B_ * E_) return;
  int m = idx / E_, j = idx - m * E_;
  float s = 0.f;
#pragma unroll
  for (int kc = 0; kc < 8; kc++) s += partial[((long)kc * B_ + m) * 208 + j];
  float s2 = g2[j] * rsqrtf(v2[j] + 1e-5f);
  float h = (s + fcb[j] - m2[j]) * s2 + b2[j];
  hbuf[idx] = f2bf(fmaxf(h, 0.f));
}

// ---------------- out = sigmoid(h @ entity^T + bias) -> d_out[1024][50000] fp32 ----------------
// 256m x 128n tile, 512 threads (8 waves, each owns 32 rows x 128 cols).
// B tile staged once in LDS, fragment-major Blds[ks(7)][quad(4)][np(128)][8 bf16];
// np = nf*16 + l16 <-> col 8*l16 + nf (lane owns 8 consecutive cols -> 2x dwordx4 stores).
// K zero-padded to 224 so the B side of the k-loop is uniform. Bijective XCD swizzle
// over 1564 blocks; each XCD's entb slice ~2.5 MB fits its 4 MB L2.
__global__ __launch_bounds__(512, 4) void k_gemm_out(
    const unsigned short* __restrict__ hbuf, const unsigned short* __restrict__ entb,
    const float* __restrict__ bias, float* __restrict__ out) {
  __shared__ __align__(16) unsigned short Blds[7 * 4 * 128 * 8];  // 57,344 B
  int g = blockIdx.x;                       // 0..1563
  int xcd = g & 7, local_ = g >> 3;         // dispatch round-robins XCDs
  int T = (xcd < 4 ? xcd * 196 : 784 + (xcd - 4) * 195) + local_;
  int mt = T & 3, nt = T >> 2;
  int m0 = mt * 256, n0 = nt * 128;
  int tid = threadIdx.x;

  // ---- stage B tile: 3584 chunks of 16 B, fragment-major, zero-padded ----
#pragma unroll
  for (int it = 0; it < 7; ++it) {
    int idx = it * 512 + tid;               // [ks][quad][np]
    int ks = idx >> 9, qd = (idx >> 7) & 3, np = idx & 127;
    int col = 8 * (np & 15) + (np >> 4);    // interleaved col within n-tile
    int n = n0 + col;
    int kb = ks * 32 + qd * 8;
    short8 v = {0, 0, 0, 0, 0, 0, 0, 0};
    if (kb < 200 && n < NE_) v = *(const short8*)(entb + (long)n * E_ + kb);
    *(short8*)(Blds + idx * 8) = v;
  }
  __syncthreads();

  int lane = tid & 63, wv = tid >> 6;       // wv 0..7
  int l16 = lane & 15, quad = lane >> 4;
  const unsigned short* ap0 = hbuf + (long)(m0 + wv * 32 + l16) * E_ + quad * 8;
  const unsigned short* ap1 = ap0 + 16 * E_;

  floatx4 acc[16];
#pragma unroll
  for (int i = 0; i < 16; ++i) acc[i] = (floatx4){0.f, 0.f, 0.f, 0.f};

#pragma unroll
  for (int ks = 0; ks < 6; ++ks) {
    short8 a0 = *(const short8*)(ap0 + ks * 32);
    short8 a1 = *(const short8*)(ap1 + ks * 32);
    const unsigned short* bb = Blds + (ks * 4 + quad) * 1024 + l16 * 8;
#pragma unroll
    for (int nf = 0; nf < 8; ++nf) {
      short8 b = *(const short8*)(bb + nf * 128);
      acc[nf]     = __builtin_amdgcn_mfma_f32_16x16x32_bf16(a0, b, acc[nf], 0, 0, 0);
      acc[8 + nf] = __builtin_amdgcn_mfma_f32_16x16x32_bf16(a1, b, acc[8 + nf], 0, 0, 0);
    }
  }
  { // k remainder 192..199: A real on quad 0 only; B pad chunks are zeros
    short8 z = {0, 0, 0, 0, 0, 0, 0, 0};
    short8 a0 = (quad == 0) ? *(const short8*)(ap0 + 192) : z;
    short8 a1 = (quad == 0) ? *(const short8*)(ap1 + 192) : z;
    const unsigned short* bb = Blds + (24 + quad) * 1024 + l16 * 8;
#pragma unroll
    for (int nf = 0; nf < 8; ++nf) {
      short8 b = *(const short8*)(bb + nf * 128);
      acc[nf]     = __builtin_amdgcn_mfma_f32_16x16x32_bf16(a0, b, acc[nf], 0, 0, 0);
      acc[8 + nf] = __builtin_amdgcn_mfma_f32_16x16x32_bf16(a1, b, acc[8 + nf], 0, 0, 0);
    }
  }

  int nb = n0 + 8 * l16;                    // lane's base output col (8-aligned)
  if (nb >= NE_) return;                    // NE%8==0 -> whole 8-col group valid or not
  float4 bi0 = *(const float4*)(bias + nb);
  float4 bi1 = *(const float4*)(bias + nb + 4);
#pragma unroll
  for (int mf = 0; mf < 2; ++mf) {
#pragma unroll
    for (int i = 0; i < 4; ++i) {
      int row = m0 + wv * 32 + mf * 16 + quad * 4 + i;
      float4 v0, v1;
      v0.x = 1.f / (1.f + __expf(-(acc[mf * 8 + 0][i] + bi0.x)));
      v0.y = 1.f / (1.f + __expf(-(acc[mf * 8 + 1][i] + bi0.y)));
      v0.z = 1.f / (1.f + __expf(-(acc[mf * 8 + 2][i] + bi0.z)));
      v0.w = 1.f / (1.f + __expf(-(acc[mf * 8 + 3][i] + bi0.w)));
      v1.x = 1.f / (1.f + __expf(-(acc[mf * 8 + 4][i] + bi1.x)));
      v1.y = 1.f / (1.f + __expf(-(acc[mf * 8 + 5][i] + bi1.y)));
      v1.z = 1.f / (1.f + __expf(-(acc[mf * 8 + 6][i] + bi1.z)));
      v1.w = 1.f / (1.f + __expf(-(acc[mf * 8 + 7][i] + bi1.w)));
      float* op = out + (long)row * NE_ + nb;
      *(float4*)op = v0;
      *(float4*)(op + 4) = v1;
    }
  }
}

extern "C" void kernel_launch(void* const* d_in, const int* in_sizes, int n_in,
                              void* d_out, int out_size, void* d_ws, size_t ws_size,
                              hipStream_t stream) {
  const int* e_s = (const int*)d_in[0];
  const int* q_s = (const int*)d_in[1];
  const int* e_c = (const int*)d_in[2];
  const float* ent  = (const float*)d_in[3];
  const float* rel  = (const float*)d_in[4];
  const float* W1w  = (const float*)d_in[5];
  const float* W1b  = (const float*)d_in[6];
  const float* fc1w = (const float*)d_in[7];
  const float* fc1b = (const float*)d_in[8];
  const float* fcw  = (const float*)d_in[9];
  const float* fcb  = (const float*)d_in[10];
  const float* g0 = (const float*)d_in[11];
  const float* b0 = (const float*)d_in[12];
  const float* m0 = (const float*)d_in[13];
  const float* v0 = (const float*)d_in[14];
  const float* g1 = (const float*)d_in[15];
  const float* b1 = (const float*)d_in[16];
  const float* m1 = (const float*)d_in[17];
  const float* v1 = (const float*)d_in[18];
  const float* g2 = (const float*)d_in[19];
  const float* b2 = (const float*)d_in[20];
  const float* m2 = (const float*)d_in[21];
  const float* v2 = (const float*)d_in[22];
  const float* bias = (const float*)d_in[23];
  float* out = (float*)d_out;

  // Workspace layout (256 B padded regions; total ~44.9 MB)
  char* w = (char*)d_ws;
  unsigned short* entb = (unsigned short*)(w + 0);          // 20,000,000 B [50000][200]
  unsigned short* cat  = (unsigned short*)(w + 20000256);   //    819,200 B [1024][400]
  unsigned short* rbuf = (unsigned short*)(w + 20819712);   //    409,600 B [1024][200]
  unsigned short* W1T  = (unsigned short*)(w + 21229568);   //    166,400 B [208][400]
  unsigned short* fc1T = (unsigned short*)(w + 21396224);   //    115,200 B [288][200]
  unsigned short* fcwT = (unsigned short*)(w + 21511680);   //  2,555,904 B [208][6144]
  unsigned short* xbuf = (unsigned short*)(w + 24067840);   //    409,600 B [1024][200]
  unsigned short* kbuf = (unsigned short*)(w + 24477696);   //    589,824 B [1024][288]
  unsigned short* flat = (unsigned short*)(w + 25067776);   // 12,582,912 B [1024][6144]
  unsigned short* hbuf = (unsigned short*)(w + 37650944);   //    409,600 B [1024][200]
  float* partial       = (float*)(w + 38060800);            //  6,815,744 B [8][1024][208]
  // end = 44,876,544

  k_prep<<<dim3(PREP_TOTAL), dim3(256), 0, stream>>>(
      ent, rel, e_s, q_s, e_c, W1w, fc1w, fcw, entb, cat, rbuf, W1T, fc1T, fcwT);
  k_gemm_ek<<<dim3(496), dim3(256), 0, stream>>>(
      cat, W1T, W1b, g0, b0, m0, v0, xbuf, rbuf, fc1T, fc1b, g1, v1, kbuf);
  k_conv<<<dim3(B_), dim3(256), 0, stream>>>(xbuf, kbuf, g1, b1, m1, v1, flat);
  k_gemm_fc<<<dim3(16, 13, 8), dim3(256), 0, stream>>>(flat, fcwT, partial);
  k_fc_epi<<<dim3((B_ * E_ + 255) / 256), dim3(256), 0, stream>>>(
      partial, fcb, g2, b2, m2, v2, hbuf);
  k_gemm_out<<<dim3(1564), dim3(512), 0, stream>>>(hbuf, entb, bias, out);
}